// Round 5
// baseline (91.982 us; speedup 1.0000x reference)
//
#include <hip/hip_runtime.h>

#define C_TOT 64
#define Dd 48
#define Hh 128
#define Ww 128
#define HW (Hh*Ww)
#define DHW (Dd*HW)
#define CSPLIT 8            // channels per block
#define SR 36               // stage row stride (floats)
#define SPL (34*36)         // stage plane stride
#define STAGE_N (8*34*36)   // 9792 floats
#define MAXPRE 9            // max staged elements per thread

typedef float lf2 __attribute__((ext_vector_type(2), aligned(4)));

__device__ __forceinline__ void axis_interp(float c, int dim, int& lo, int& hi,
                                            float& fr, bool& valid) {
    valid = (c >= -1.0f) && (c <= (float)dim);
    c = fminf(fmaxf(c, 0.0f), (float)(dim - 1));
    float l = floorf(c);
    lo = (int)l;
    hi = min(lo + 1, dim - 1);
    fr = c - l;
}

__global__ __launch_bounds__(1024) void roialign_avg3d_kernel(
    const float* __restrict__ feats, const float* __restrict__ rois,
    float* __restrict__ out)
{
    const int r    = blockIdx.x;   // roi
    const int cb   = blockIdx.y;   // channel octet 0..7
    const int tid  = threadIdx.x;
    const int wave = tid >> 6;
    const int lane = tid & 63;
    const int xb   = lane & 7;     // x-bin (lane covers both its x-samples)
    const int ysi  = lane >> 3;    // y-sample sub-index 0..7
    const int zsl  = wave & 7;     // z-sample within half
    const int yg   = wave >> 3;    // y-sample group (0: ys 0..7, 1: ys 8..15)

    __shared__ float stage[STAGE_N];
    __shared__ float bins[16 * 64];   // [zs][yb*8+xb]

    for (int i = tid; i < STAGE_N; i += 1024) stage[i] = 0.0f;  // safety init

    // --- roi params (block-uniform) ---
    const float* rr = rois + r * 7;
    const int   b  = (int)rr[0];
    const float x1 = rr[1] * 0.25f, y1v = rr[2] * 0.25f, z1v = rr[3] * 0.25f;
    const float x2 = rr[4] * 0.25f, y2v = rr[5] * 0.25f, z2v = rr[6] * 0.25f;
    const float rw = fmaxf(x2 - x1, 1.0f);
    const float rh = fmaxf(y2v - y1v, 1.0f);
    const float rd = fmaxf(z2v - z1v, 1.0f);
    const float bsx = rw * 0.125f, bsy = rh * 0.125f, bsz = rd * 0.125f;

    // --- staged region: x,y shared by both halves; z per half ---
    const float xc0f = x1 + 0.25f * bsx, xc15f = x1 + 7.75f * bsx;
    int x0   = (int)floorf(fminf(fmaxf(xc0f, 0.0f), 127.0f));
    int xhiR = min((int)floorf(fminf(fmaxf(xc15f, 0.0f), 127.0f)) + 1, Ww - 1);
    int xext = xhiR - x0 + 1;
    if (xext < 4) xext = 4;
    if (x0 + xext > Ww) x0 = Ww - xext;   // shift window; corners stay inside

    const float yc0f = y1v + 0.25f * bsy, yc15f = y1v + 7.75f * bsy;
    int y0   = (int)floorf(fminf(fmaxf(yc0f, 0.0f), 127.0f));
    int yhiR = min((int)floorf(fminf(fmaxf(yc15f, 0.0f), 127.0f)) + 1, Hh - 1);
    const int yext = yhiR - y0 + 1;

    int p0[2], pext[2];
    #pragma unroll
    for (int h = 0; h < 2; ++h) {
        const float zf = z1v + ((float)(4 * h) + 0.25f) * bsz;       // zc(8h)
        const float zl = z1v + ((float)(4 * h + 3) + 0.75f) * bsz;   // zc(8h+7)
        const int pp0  = (int)floorf(fminf(fmaxf(zf, 0.0f), 47.0f));
        const int pphi = min((int)floorf(fminf(fmaxf(zl, 0.0f), 47.0f)) + 1, Dd - 1);
        p0[h] = pp0; pext[h] = pphi - pp0 + 1;                       // <= 8
    }

    // --- x window weights (per lane, fixed) ---
    const float xcA = x1 + (float)xb * bsx + 0.25f * bsx;
    const float xcB = x1 + (float)xb * bsx + 0.75f * bsx;
    int xloA, xhiA, xloB, xhiB; float fxA, fxB; bool vxA, vxB;
    axis_interp(xcA, Ww, xloA, xhiA, fxA, vxA);
    axis_interp(xcB, Ww, xloB, xhiB, fxB, vxB);
    const int bAbs = min(xloA, x0 + xext - 4);
    const int bx   = bAbs - x0;
    float w0 = 0.0f, w1 = 0.0f, w2 = 0.0f, w3 = 0.0f;
    {
        const int iA = xloA - bAbs, hA = xhiA - bAbs;
        const int iB = xloB - bAbs, hB = xhiB - bAbs;
        const float a0 = vxA ? (1.0f - fxA) : 0.0f, a1 = vxA ? fxA : 0.0f;
        const float b0 = vxB ? (1.0f - fxB) : 0.0f, b1 = vxB ? fxB : 0.0f;
        w0 += (iA == 0) ? a0 : 0.0f; w1 += (iA == 1) ? a0 : 0.0f; w2 += (iA == 2) ? a0 : 0.0f; w3 += (iA == 3) ? a0 : 0.0f;
        w0 += (hA == 0) ? a1 : 0.0f; w1 += (hA == 1) ? a1 : 0.0f; w2 += (hA == 2) ? a1 : 0.0f; w3 += (hA == 3) ? a1 : 0.0f;
        w0 += (iB == 0) ? b0 : 0.0f; w1 += (iB == 1) ? b0 : 0.0f; w2 += (iB == 2) ? b0 : 0.0f; w3 += (iB == 3) ? b0 : 0.0f;
        w0 += (hB == 0) ? b1 : 0.0f; w1 += (hB == 1) ? b1 : 0.0f; w2 += (hB == 2) ? b1 : 0.0f; w3 += (hB == 3) ? b1 : 0.0f;
    }

    // --- y interp (per lane) ---
    const int ys = yg * 8 + ysi;
    const float yc = y1v + (float)(ys >> 1) * bsy + ((float)(ys & 1) + 0.5f) * 0.5f * bsy;
    int ylo, yhi; float fy; bool vy;
    axis_interp(yc, Hh, ylo, yhi, fy, vy);
    const int ly0 = ylo - y0, ly1 = yhi - y0;
    const int yb  = ys >> 1;

    // --- z interp per half: row weights + LDS addresses (fixed across channels) ---
    float wrow[2][4];
    int   adr[2][4];
    #pragma unroll
    for (int h = 0; h < 2; ++h) {
        const int zs = 8 * h + zsl;
        const float zc = z1v + (float)(zs >> 1) * bsz + ((float)(zs & 1) + 0.5f) * 0.5f * bsz;
        int zlo, zhi; float fz; bool vz;
        axis_interp(zc, Dd, zlo, zhi, fz, vz);
        const float s  = (vy && vz) ? 1.0f : 0.0f;
        const float wz0 = 1.0f - fz, wz1 = fz;
        const float wy0 = 1.0f - fy, wy1 = fy;
        wrow[h][0] = s * wz0 * wy0; wrow[h][1] = s * wz0 * wy1;
        wrow[h][2] = s * wz1 * wy0; wrow[h][3] = s * wz1 * wy1;
        const int pz0 = zlo - p0[h], pz1 = zhi - p0[h];
        adr[h][0] = (pz0 * 34 + ly0) * SR + bx;
        adr[h][1] = (pz0 * 34 + ly1) * SR + bx;
        adr[h][2] = (pz1 * 34 + ly0) * SR + bx;
        adr[h][3] = (pz1 * 34 + ly1) * SR + bx;
    }

    // --- staging decomposition (fixed per thread; init-only divisions) ---
    const int rowN = yext * xext;
    int soff[MAXPRE], goff[MAXPRE], pk[MAXPRE];
    #pragma unroll
    for (int k = 0; k < MAXPRE; ++k) {
        const int idx = tid + k * 1024;
        const int p   = idx / rowN;
        const int rem = idx - p * rowN;
        const int yy  = rem / xext;
        const int xx  = rem - yy * xext;
        pk[k]   = p;
        soff[k] = (p * 34 + yy) * SR + xx;
        goff[k] = p * HW + (y0 + yy) * Ww + (x0 + xx);
    }

    const float* fb = feats + (size_t)(b * C_TOT + cb * CSPLIT) * (size_t)DHW;

    // --- prefetch phase (0,0) ---
    float pre[MAXPRE];
    {
        const float* gp = fb + (size_t)p0[0] * HW;
        #pragma unroll
        for (int k = 0; k < MAXPRE; ++k)
            pre[k] = (pk[k] < pext[0]) ? gp[goff[k]] : 0.0f;
    }

    for (int c = 0; c < CSPLIT; ++c) {
        #pragma unroll
        for (int h = 0; h < 2; ++h) {
            __syncthreads();   // prev sampling + pooling done; stage safe to overwrite
            #pragma unroll
            for (int k = 0; k < MAXPRE; ++k)
                if (pk[k] < pext[h]) stage[soff[k]] = pre[k];
            // issue next phase's global loads (latency hides under sampling)
            const int nc = (h == 1) ? c + 1 : c;
            const int nh = 1 - h;
            if (nc < CSPLIT) {
                const float* gp = fb + (size_t)nc * DHW + (size_t)p0[nh] * HW;
                #pragma unroll
                for (int k = 0; k < MAXPRE; ++k)
                    pre[k] = (pk[k] < pext[nh]) ? gp[goff[k]] : 0.0f;
            }
            __syncthreads();   // stage ready
            // --- sample from LDS ---
            float v = 0.0f;
            #pragma unroll
            for (int rq = 0; rq < 4; ++rq) {
                const float* sp = &stage[adr[h][rq]];
                lf2 u0 = *(const lf2*)sp;
                lf2 u1 = *(const lf2*)(sp + 2);
                const float d = u0.x * w0 + u0.y * w1 + u1.x * w2 + u1.y * w3;
                v += wrow[h][rq] * d;
            }
            v += __shfl_xor(v, 8);          // reduce y-sample pair
            if (!(ysi & 1))
                bins[(8 * h + zsl) * 64 + yb * 8 + xb] = v;
        }
        __syncthreads();   // all 16 z-slices of bins written for channel c
        // --- fused 2x2x2 stride-1 pooling + store for channel c ---
        if (tid < 343) {
            const int w_ = tid % 7, h_ = (tid / 7) % 7, dz = tid / 49;
            float acc = 0.0f;
            #pragma unroll
            for (int g = 0; g < 4; ++g) {
                const float* bz = &bins[(2 * dz + g) * 64];
                acc += bz[h_ * 8 + w_]       + bz[h_ * 8 + w_ + 1]
                     + bz[(h_ + 1) * 8 + w_] + bz[(h_ + 1) * 8 + w_ + 1];
            }
            acc *= (1.0f / 64.0f);
            const int cg = cb * CSPLIT + c;
            out[(((size_t)r * C_TOT + cg) * 7 + dz) * 49 + h_ * 7 + w_] = acc;
        }
    }
}

extern "C" void kernel_launch(void* const* d_in, const int* in_sizes, int n_in,
                              void* d_out, int out_size, void* d_ws, size_t ws_size,
                              hipStream_t stream) {
    const float* feats = (const float*)d_in[0];
    const float* rois  = (const float*)d_in[1];
    float* out = (float*)d_out;
    const int R = in_sizes[1] / 7;   // 64
    dim3 grid(R, C_TOT / CSPLIT);
    roialign_avg3d_kernel<<<grid, 1024, 0, stream>>>(feats, rois, out);
}